// Round 3
// baseline (433.412 us; speedup 1.0000x reference)
//
#include <hip/hip_runtime.h>

#define NPTS 8192

// ws layout (floats): yc [0,131072) ; wtr [131072,196608) ; wti [196608,262144)
// d_out's first 524288 floats double as Xp scratch:
//   Xp[((seg*16+k)*2+c)*4096 + row], seg<4, c=0 re/1 im, row = b*64 + in_ch.
// Order: dft writes Xp -> mix reads Xp -> synth overwrites all of d_out.

__global__ __launch_bounds__(256) void prep_kernel(const float* __restrict__ wr,
                                                   const float* __restrict__ wi,
                                                   float* __restrict__ wtr,
                                                   float* __restrict__ wti) {
    int idx = blockIdx.x * 256 + threadIdx.x;       // [0, 65536)
    int i = idx >> 10, o = (idx >> 4) & 63, k = idx & 15;
    int dst = k * 4096 + i * 64 + o;
    wtr[dst] = wr[idx];
    wti[dst] = wi[idx];
}

// Stage 1: truncated DFT. grid 1024 = 256 row-blocks(16 rows) x 4 n-segments.
// 8 groups of 32 lanes; group owns 8 rows x 4 modes. Basis lives in VGPRs,
// advanced per 128-n chunk by exact rotation cos/sin(pi*k/32). x staging is
// register-pipelined (load next chunk during compute of current).
__global__ __launch_bounds__(256) void dft_kernel(const float* __restrict__ x,
                                                  float* __restrict__ Xp) {
    __shared__ float smem[8448];     // 8 KB x-chunk during main loop; 33 KB reduce buf after
    float* xs = smem;
    const int t = threadIdx.x;
    const int rb = blockIdx.x >> 2, seg = blockIdx.x & 3;
    const int rowbase = rb * 16, segbase = seg * 2048;
    const int lane = t & 31, grp = t >> 5;
    const int r0 = (grp & 1) * 8;
    const int k0 = (grp >> 1) * 4;

    // basis init at chunk 0 via exact integer phase: theta = pi*((k*n)&8191)/4096
    float2 cv[2][4], sv[2][4];
#pragma unroll
    for (int i = 0; i < 2; ++i)
#pragma unroll
        for (int j = 0; j < 4; ++j) {
            int k = k0 + j;
            int n = segbase + i * 64 + lane * 2;
            int p0 = (k * n) & 8191;
            int p1 = (k * (n + 1)) & 8191;
            cv[i][j] = make_float2(cospif(p0 * (1.0f / 4096.0f)),
                                   cospif(p1 * (1.0f / 4096.0f)));
            sv[i][j] = make_float2(sinpif(p0 * (1.0f / 4096.0f)),
                                   sinpif(p1 * (1.0f / 4096.0f)));
        }
    float cd[4], sd[4];              // rotation per 128-n chunk: delta = pi*k/32
#pragma unroll
    for (int j = 0; j < 4; ++j) {
        cd[j] = cospif((k0 + j) * (1.0f / 32.0f));
        sd[j] = sinpif((k0 + j) * (1.0f / 32.0f));
    }

    float ar[8][4] = {{0.f}}, ai[8][4] = {{0.f}};

    float4 cur[2];
#pragma unroll
    for (int jj = 0; jj < 2; ++jj) {
        int p = t + jj * 256;
        cur[jj] = *(const float4*)&x[(rowbase + (p >> 5)) * NPTS + segbase + (p & 31) * 4];
    }

    for (int ch = 0; ch < 16; ++ch) {
        __syncthreads();             // readers of previous chunk done
#pragma unroll
        for (int jj = 0; jj < 2; ++jj)
            ((float4*)xs)[t + jj * 256] = cur[jj];
        __syncthreads();
        if (ch < 15) {               // prefetch next chunk; latency hides behind compute
            const int base = segbase + (ch + 1) * 128;
#pragma unroll
            for (int jj = 0; jj < 2; ++jj) {
                int p = t + jj * 256;
                cur[jj] = *(const float4*)&x[(rowbase + (p >> 5)) * NPTS + base + (p & 31) * 4];
            }
        }
        const float2* xs2 = (const float2*)xs;
#pragma unroll
        for (int i = 0; i < 2; ++i) {
            float2 xv[8];
#pragma unroll
            for (int r = 0; r < 8; ++r) xv[r] = xs2[(r0 + r) * 64 + i * 32 + lane];
#pragma unroll
            for (int r = 0; r < 8; ++r)
#pragma unroll
                for (int j = 0; j < 4; ++j) {
                    ar[r][j] += xv[r].x * cv[i][j].x + xv[r].y * cv[i][j].y;
                    ai[r][j] -= xv[r].x * sv[i][j].x + xv[r].y * sv[i][j].y;
                }
        }
        if (ch < 15) {               // advance basis by one chunk
#pragma unroll
            for (int i = 0; i < 2; ++i)
#pragma unroll
                for (int j = 0; j < 4; ++j) {
                    float cx = cv[i][j].x * cd[j] - sv[i][j].x * sd[j];
                    float sx = sv[i][j].x * cd[j] + cv[i][j].x * sd[j];
                    float cy = cv[i][j].y * cd[j] - sv[i][j].y * sd[j];
                    float sy = sv[i][j].y * cd[j] + cv[i][j].y * sd[j];
                    cv[i][j] = make_float2(cx, cy);
                    sv[i][j] = make_float2(sx, sy);
                }
        }
    }

    // 2-phase conflict-free LDS reduction over each group's 32 lanes.
    // layout: smem[g*1056 + o*33 + lane], o = r*4+j.
    __syncthreads();
#pragma unroll
    for (int r = 0; r < 8; ++r)
#pragma unroll
        for (int j = 0; j < 4; ++j)
            smem[grp * 1056 + (r * 4 + j) * 33 + lane] = ar[r][j];
    __syncthreads();
    {
        float s = 0.f;
#pragma unroll
        for (int l = 0; l < 32; ++l) s += smem[grp * 1056 + lane * 33 + l];
        int r = lane >> 2, j = lane & 3;
        int row = rowbase + (grp & 1) * 8 + r;
        int k = (grp >> 1) * 4 + j;
        Xp[((seg * 16 + k) * 2 + 0) * 4096 + row] = s;
    }
    __syncthreads();
#pragma unroll
    for (int r = 0; r < 8; ++r)
#pragma unroll
        for (int j = 0; j < 4; ++j)
            smem[grp * 1056 + (r * 4 + j) * 33 + lane] = ai[r][j];
    __syncthreads();
    {
        float s = 0.f;
#pragma unroll
        for (int l = 0; l < 32; ++l) s += smem[grp * 1056 + lane * 33 + l];
        int r = lane >> 2, j = lane & 3;
        int row = rowbase + (grp & 1) * 8 + r;
        int k = (grp >> 1) * 4 + j;
        Xp[((seg * 16 + k) * 2 + 1) * 4096 + row] = s;
    }
}

// Stage 2: channel mix. grid 64 = 16 modes x 4 batch-quarters.
__global__ __launch_bounds__(256) void mix_kernel(const float* __restrict__ Xp,
                                                  const float* __restrict__ wtr,
                                                  const float* __restrict__ wti,
                                                  float* __restrict__ yc) {
    __shared__ float xre[16 * 65], xim[16 * 65];
    __shared__ float wlr[4096], wli[4096];
    const int t = threadIdx.x;
    const int k = blockIdx.x & 15, bq = blockIdx.x >> 4;
#pragma unroll
    for (int j = 0; j < 4; ++j) {
        int lr = t + j * 256;                   // local row [0,1024)
        int row = bq * 1024 + lr;
        float re = 0.f, im = 0.f;
#pragma unroll
        for (int s = 0; s < 4; ++s) {
            re += Xp[((s * 16 + k) * 2 + 0) * 4096 + row];
            im += Xp[((s * 16 + k) * 2 + 1) * 4096 + row];
        }
        xre[(lr >> 6) * 65 + (lr & 63)] = re;
        xim[(lr >> 6) * 65 + (lr & 63)] = im;
        ((float4*)wlr)[t + j * 256] = ((const float4*)(wtr + k * 4096))[t + j * 256];
        ((float4*)wli)[t + j * 256] = ((const float4*)(wti + k * 4096))[t + j * 256];
    }
    __syncthreads();
    const int bt = t >> 4;                      // local batch 0..15
    const int o4 = t & 15;                      // out_ch quad
    float accr[4] = {0.f, 0.f, 0.f, 0.f}, acci[4] = {0.f, 0.f, 0.f, 0.f};
    for (int i = 0; i < 64; ++i) {
        float xr = xre[bt * 65 + i], xi = xim[bt * 65 + i];
        float4 w4r = ((const float4*)wlr)[i * 16 + o4];
        float4 w4i = ((const float4*)wli)[i * 16 + o4];
        accr[0] += xr * w4r.x - xi * w4i.x;  acci[0] += xr * w4i.x + xi * w4r.x;
        accr[1] += xr * w4r.y - xi * w4i.y;  acci[1] += xr * w4i.y + xi * w4r.y;
        accr[2] += xr * w4r.z - xi * w4i.z;  acci[2] += xr * w4i.z + xi * w4r.z;
        accr[3] += xr * w4r.w - xi * w4i.w;  acci[3] += xr * w4i.w + xi * w4r.w;
    }
    const float invn = 1.0f / 8192.0f;
#pragma unroll
    for (int oo = 0; oo < 4; ++oo) {
        int row = (bq * 16 + bt) * 64 + o4 * 4 + oo;
        if (k == 0) {
            yc[row * 32]      = accr[oo] * invn;
            yc[row * 32 + 16] = 0.f;
        } else {
            yc[row * 32 + k]      = 2.f * accr[oo] * invn;
            yc[row * 32 + 16 + k] = -2.f * acci[oo] * invn;
        }
    }
}

// Stage 3: synthesis. grid 512 = 256 row-groups(16 rows) x 2 n-halves.
// Basis in 128 VGPRs (cospif init), stepped by exact 45-degree-multiple
// rotations (stride 1024). Coefs via wave-uniform scalar loads.
__global__ __launch_bounds__(256) void synth_kernel(const float* __restrict__ yc,
                                                    float* __restrict__ out) {
    const int t = threadIdx.x;
    const int rg = blockIdx.x >> 1, q = blockIdx.x & 1;
    const int n0 = q * 4096 + t * 4;
    float4 cb[16], sb[16];
#pragma unroll
    for (int k = 0; k < 16; ++k) {
        int p0 = (k * (n0 + 0)) & 8191;
        int p1 = (k * (n0 + 1)) & 8191;
        int p2 = (k * (n0 + 2)) & 8191;
        int p3 = (k * (n0 + 3)) & 8191;
        cb[k] = make_float4(cospif(p0 * (1.0f / 4096.0f)), cospif(p1 * (1.0f / 4096.0f)),
                            cospif(p2 * (1.0f / 4096.0f)), cospif(p3 * (1.0f / 4096.0f)));
        sb[k] = make_float4(sinpif(p0 * (1.0f / 4096.0f)), sinpif(p1 * (1.0f / 4096.0f)),
                            sinpif(p2 * (1.0f / 4096.0f)), sinpif(p3 * (1.0f / 4096.0f)));
    }
    const float R2 = 0.70710678118654752440f;
    const float CD[8] = {1.f, R2, 0.f, -R2, -1.f, -R2, 0.f, R2};   // cos(pi*k/4)
    const float SD[8] = {0.f, R2, 1.f, R2, 0.f, -R2, -1.f, -R2};   // sin(pi*k/4)
#pragma unroll
    for (int j = 0; j < 4; ++j) {
#pragma unroll 2
        for (int r = 0; r < 16; ++r) {
            int row = rg * 16 + r;
            const float* cf = &yc[row * 32];        // wave-uniform -> s_load
            float ax = 0.f, ay = 0.f, az = 0.f, aw = 0.f;
#pragma unroll
            for (int k = 0; k < 16; ++k) {
                float cc = cf[k], sc = cf[16 + k];
                ax += cc * cb[k].x + sc * sb[k].x;
                ay += cc * cb[k].y + sc * sb[k].y;
                az += cc * cb[k].z + sc * sb[k].z;
                aw += cc * cb[k].w + sc * sb[k].w;
            }
            *(float4*)&out[row * NPTS + n0 + j * 1024] = make_float4(ax, ay, az, aw);
        }
        if (j < 3) {
#pragma unroll
            for (int k = 0; k < 16; ++k) {
                float cdk = CD[k & 7], sdk = SD[k & 7];
                float4 c = cb[k], s = sb[k];
                cb[k] = make_float4(c.x * cdk - s.x * sdk, c.y * cdk - s.y * sdk,
                                    c.z * cdk - s.z * sdk, c.w * cdk - s.w * sdk);
                sb[k] = make_float4(s.x * cdk + c.x * sdk, s.y * cdk + c.y * sdk,
                                    s.z * cdk + c.z * sdk, s.w * cdk + c.w * sdk);
            }
        }
    }
}

extern "C" void kernel_launch(void* const* d_in, const int* in_sizes, int n_in,
                              void* d_out, int out_size, void* d_ws, size_t ws_size,
                              hipStream_t stream) {
    const float* x  = (const float*)d_in[0];
    const float* wr = (const float*)d_in[1];
    const float* wi = (const float*)d_in[2];
    float* out = (float*)d_out;
    float* ws  = (float*)d_ws;
    float* yc  = ws;
    float* wtr = ws + 131072;
    float* wti = ws + 196608;
    float* Xp  = out;   // scratch; overwritten by synth

    prep_kernel<<<256, 256, 0, stream>>>(wr, wi, wtr, wti);
    dft_kernel<<<1024, 256, 0, stream>>>(x, Xp);
    mix_kernel<<<64, 256, 0, stream>>>(Xp, wtr, wti, yc);
    synth_kernel<<<512, 256, 0, stream>>>(yc, out);
}

// Round 4
// 310.175 us; speedup vs baseline: 1.3973x; 1.3973x over previous
//
#include <hip/hip_runtime.h>

#define NPTS 8192

// ws layout (floats): yc [0,131072) ; wtr [131072,196608) ; wti [196608,262144)
// d_out's first 1M floats double as Xp scratch:
//   Xp[((seg*16+k)*2+c)*4096 + row], seg<8, c=0 re/1 im, row = b*64 + in_ch.
// Order: dft writes Xp -> mix reads Xp -> synth overwrites all of d_out.

__global__ __launch_bounds__(256) void prep_kernel(const float* __restrict__ wr,
                                                   const float* __restrict__ wi,
                                                   float* __restrict__ wtr,
                                                   float* __restrict__ wti) {
    int idx = blockIdx.x * 256 + threadIdx.x;       // [0, 65536)
    int i = idx >> 10, o = (idx >> 4) & 63, k = idx & 15;
    int dst = k * 4096 + i * 64 + o;
    wtr[dst] = wr[idx];
    wti[dst] = wi[idx];
}

// Stage 1: truncated DFT. grid 2048 = 256 row-blocks(16 rows) x 8 n-segments(1024).
// 8 groups of 32 lanes; group owns 8 rows x 4 modes. Basis in VGPRs, rotated
// per 128-n chunk. Depth-2 register prefetch + double-buffered LDS chunks.
__global__ __launch_bounds__(256) void dft_kernel(const float* __restrict__ x,
                                                  float* __restrict__ Xp) {
    __shared__ float smem[8448];   // [0,2048)/[2048,4096): x dbuf; full: reduce buf
    const int t = threadIdx.x;
    const int rb = blockIdx.x >> 3, seg = blockIdx.x & 7;
    const int rowbase = rb * 16, segbase = seg * 1024;
    const int lane = t & 31, grp = t >> 5;
    const int r0 = (grp & 1) * 8;
    const int k0 = (grp >> 1) * 4;

    // basis init via exact integer phase: theta = pi*((k*n)&8191)/4096
    float2 cv[2][4], sv[2][4];
#pragma unroll
    for (int i = 0; i < 2; ++i)
#pragma unroll
        for (int j = 0; j < 4; ++j) {
            int k = k0 + j;
            int n = segbase + i * 64 + lane * 2;
            int p0 = (k * n) & 8191;
            int p1 = (k * (n + 1)) & 8191;
            cv[i][j] = make_float2(cospif(p0 * (1.0f / 4096.0f)),
                                   cospif(p1 * (1.0f / 4096.0f)));
            sv[i][j] = make_float2(sinpif(p0 * (1.0f / 4096.0f)),
                                   sinpif(p1 * (1.0f / 4096.0f)));
        }
    float cd[4], sd[4];            // per-chunk rotation: delta = pi*k/32
#pragma unroll
    for (int j = 0; j < 4; ++j) {
        cd[j] = cospif((k0 + j) * (1.0f / 32.0f));
        sd[j] = sinpif((k0 + j) * (1.0f / 32.0f));
    }

    float ar[8][4] = {{0.f}}, ai[8][4] = {{0.f}};

    float4 A[2], B[2];
#define LOADX(c, dst)                                                              \
    {                                                                              \
        _Pragma("unroll") for (int jj = 0; jj < 2; ++jj) {                         \
            int p = t + jj * 256;                                                  \
            dst[jj] = *(const float4*)&x[(rowbase + (p >> 5)) * NPTS + segbase +   \
                                         (c) * 128 + (p & 31) * 4];                \
        }                                                                          \
    }
#define COMPUTE(bufofs)                                                            \
    {                                                                              \
        const float2* xs2 = (const float2*)(smem + (bufofs));                      \
        _Pragma("unroll") for (int i = 0; i < 2; ++i) {                            \
            float2 xv[8];                                                          \
            _Pragma("unroll") for (int r = 0; r < 8; ++r)                          \
                xv[r] = xs2[(r0 + r) * 64 + i * 32 + lane];                        \
            _Pragma("unroll") for (int r = 0; r < 8; ++r)                          \
                _Pragma("unroll") for (int j = 0; j < 4; ++j) {                    \
                    ar[r][j] += xv[r].x * cv[i][j].x + xv[r].y * cv[i][j].y;       \
                    ai[r][j] -= xv[r].x * sv[i][j].x + xv[r].y * sv[i][j].y;       \
                }                                                                  \
        }                                                                          \
    }
#define ROTATE()                                                                   \
    {                                                                              \
        _Pragma("unroll") for (int i = 0; i < 2; ++i)                              \
            _Pragma("unroll") for (int j = 0; j < 4; ++j) {                        \
                float cx = cv[i][j].x * cd[j] - sv[i][j].x * sd[j];                \
                float sx = sv[i][j].x * cd[j] + cv[i][j].x * sd[j];                \
                float cy = cv[i][j].y * cd[j] - sv[i][j].y * sd[j];                \
                float sy = sv[i][j].y * cd[j] + cv[i][j].y * sd[j];                \
                cv[i][j] = make_float2(cx, cy);                                    \
                sv[i][j] = make_float2(sx, sy);                                    \
            }                                                                      \
    }

    LOADX(0, A)
    LOADX(1, B)
    for (int ch = 0; ch < 8; ch += 2) {
        __syncthreads();                             // buf0 readers (ch-2) done
        ((float4*)smem)[t] = A[0];
        ((float4*)smem)[t + 256] = A[1];
        if (ch + 2 < 8) LOADX(ch + 2, A)             // depth-2 prefetch
        __syncthreads();
        COMPUTE(0)
        ROTATE()
        __syncthreads();                             // buf1 readers done
        ((float4*)(smem + 2048))[t] = B[0];
        ((float4*)(smem + 2048))[t + 256] = B[1];
        if (ch + 3 < 8) LOADX(ch + 3, B)
        __syncthreads();
        COMPUTE(2048)
        ROTATE()
    }

    // 2-phase conflict-free LDS reduction over each group's 32 lanes.
    __syncthreads();
#pragma unroll
    for (int r = 0; r < 8; ++r)
#pragma unroll
        for (int j = 0; j < 4; ++j)
            smem[grp * 1056 + (r * 4 + j) * 33 + lane] = ar[r][j];
    __syncthreads();
    {
        float s = 0.f;
#pragma unroll
        for (int l = 0; l < 32; ++l) s += smem[grp * 1056 + lane * 33 + l];
        int r = lane >> 2, j = lane & 3;
        int row = rowbase + (grp & 1) * 8 + r;
        int k = (grp >> 1) * 4 + j;
        Xp[((seg * 16 + k) * 2 + 0) * 4096 + row] = s;
    }
    __syncthreads();
#pragma unroll
    for (int r = 0; r < 8; ++r)
#pragma unroll
        for (int j = 0; j < 4; ++j)
            smem[grp * 1056 + (r * 4 + j) * 33 + lane] = ai[r][j];
    __syncthreads();
    {
        float s = 0.f;
#pragma unroll
        for (int l = 0; l < 32; ++l) s += smem[grp * 1056 + lane * 33 + l];
        int r = lane >> 2, j = lane & 3;
        int row = rowbase + (grp & 1) * 8 + r;
        int k = (grp >> 1) * 4 + j;
        Xp[((seg * 16 + k) * 2 + 1) * 4096 + row] = s;
    }
#undef LOADX
#undef COMPUTE
#undef ROTATE
}

// Stage 2: channel mix. grid 64 = 16 modes x 4 batch-quarters.
__global__ __launch_bounds__(256) void mix_kernel(const float* __restrict__ Xp,
                                                  const float* __restrict__ wtr,
                                                  const float* __restrict__ wti,
                                                  float* __restrict__ yc) {
    __shared__ float xre[16 * 65], xim[16 * 65];
    __shared__ float wlr[4096], wli[4096];
    const int t = threadIdx.x;
    const int k = blockIdx.x & 15, bq = blockIdx.x >> 4;
#pragma unroll
    for (int j = 0; j < 4; ++j) {
        int lr = t + j * 256;                   // local row [0,1024)
        int row = bq * 1024 + lr;
        float re = 0.f, im = 0.f;
#pragma unroll
        for (int s = 0; s < 8; ++s) {
            re += Xp[((s * 16 + k) * 2 + 0) * 4096 + row];
            im += Xp[((s * 16 + k) * 2 + 1) * 4096 + row];
        }
        xre[(lr >> 6) * 65 + (lr & 63)] = re;
        xim[(lr >> 6) * 65 + (lr & 63)] = im;
        ((float4*)wlr)[t + j * 256] = ((const float4*)(wtr + k * 4096))[t + j * 256];
        ((float4*)wli)[t + j * 256] = ((const float4*)(wti + k * 4096))[t + j * 256];
    }
    __syncthreads();
    const int bt = t >> 4;                      // local batch 0..15
    const int o4 = t & 15;                      // out_ch quad
    float accr[4] = {0.f, 0.f, 0.f, 0.f}, acci[4] = {0.f, 0.f, 0.f, 0.f};
    for (int i = 0; i < 64; ++i) {
        float xr = xre[bt * 65 + i], xi = xim[bt * 65 + i];
        float4 w4r = ((const float4*)wlr)[i * 16 + o4];
        float4 w4i = ((const float4*)wli)[i * 16 + o4];
        accr[0] += xr * w4r.x - xi * w4i.x;  acci[0] += xr * w4i.x + xi * w4r.x;
        accr[1] += xr * w4r.y - xi * w4i.y;  acci[1] += xr * w4i.y + xi * w4r.y;
        accr[2] += xr * w4r.z - xi * w4i.z;  acci[2] += xr * w4i.z + xi * w4r.z;
        accr[3] += xr * w4r.w - xi * w4i.w;  acci[3] += xr * w4i.w + xi * w4r.w;
    }
    const float invn = 1.0f / 8192.0f;
#pragma unroll
    for (int oo = 0; oo < 4; ++oo) {
        int row = (bq * 16 + bt) * 64 + o4 * 4 + oo;
        if (k == 0) {
            yc[row * 32]      = accr[oo] * invn;
            yc[row * 32 + 16] = 0.f;
        } else {
            yc[row * 32 + k]      = 2.f * accr[oo] * invn;
            yc[row * 32 + 16 + k] = -2.f * acci[oo] * invn;
        }
    }
}

// Stage 3: synthesis. grid 4096 = 256 row-groups(16 rows) x 16 n-tiles(512).
// Thread owns 2 n-points: basis = 64 VGPRs (cospif k=1 + complex-mul chain).
// Coefs staged in LDS, read as float4 broadcasts (conflict-free).
__global__ __launch_bounds__(256) void synth_kernel(const float* __restrict__ yc,
                                                    float* __restrict__ out) {
    __shared__ float cf[512];        // 16 rows x 32 coefs
    const int t = threadIdx.x;
    const int rg = blockIdx.x >> 4, tile = blockIdx.x & 15;
    cf[t]       = yc[rg * 512 + t];
    cf[t + 256] = yc[rg * 512 + 256 + t];

    const int n0 = tile * 512 + t * 2;
    float2 cb[16], sb[16];
    cb[0] = make_float2(1.f, 1.f);
    sb[0] = make_float2(0.f, 0.f);
    {
        float a0 = (float)(n0 & 8191) * (1.0f / 4096.0f);
        float a1 = (float)((n0 + 1) & 8191) * (1.0f / 4096.0f);
        cb[1] = make_float2(cospif(a0), cospif(a1));
        sb[1] = make_float2(sinpif(a0), sinpif(a1));
    }
#pragma unroll
    for (int k = 2; k < 16; ++k) {
        cb[k] = make_float2(cb[k-1].x * cb[1].x - sb[k-1].x * sb[1].x,
                            cb[k-1].y * cb[1].y - sb[k-1].y * sb[1].y);
        sb[k] = make_float2(sb[k-1].x * cb[1].x + cb[k-1].x * sb[1].x,
                            sb[k-1].y * cb[1].y + cb[k-1].y * sb[1].y);
    }
    __syncthreads();
#pragma unroll 4
    for (int r = 0; r < 16; ++r) {
        const float4* c4 = (const float4*)&cf[r * 32];
        float ax = 0.f, ay = 0.f;
#pragma unroll
        for (int j = 0; j < 4; ++j) {
            float4 a = c4[j];            // cos coefs k = 4j..4j+3
            float4 s = c4[4 + j];        // sin coefs
            ax += a.x * cb[4*j].x + a.y * cb[4*j+1].x + a.z * cb[4*j+2].x + a.w * cb[4*j+3].x
                + s.x * sb[4*j].x + s.y * sb[4*j+1].x + s.z * sb[4*j+2].x + s.w * sb[4*j+3].x;
            ay += a.x * cb[4*j].y + a.y * cb[4*j+1].y + a.z * cb[4*j+2].y + a.w * cb[4*j+3].y
                + s.x * sb[4*j].y + s.y * sb[4*j+1].y + s.z * sb[4*j+2].y + s.w * sb[4*j+3].y;
        }
        *(float2*)&out[(rg * 16 + r) * NPTS + n0] = make_float2(ax, ay);
    }
}

extern "C" void kernel_launch(void* const* d_in, const int* in_sizes, int n_in,
                              void* d_out, int out_size, void* d_ws, size_t ws_size,
                              hipStream_t stream) {
    const float* x  = (const float*)d_in[0];
    const float* wr = (const float*)d_in[1];
    const float* wi = (const float*)d_in[2];
    float* out = (float*)d_out;
    float* ws  = (float*)d_ws;
    float* yc  = ws;
    float* wtr = ws + 131072;
    float* wti = ws + 196608;
    float* Xp  = out;   // 4 MB scratch; overwritten by synth

    prep_kernel<<<256, 256, 0, stream>>>(wr, wi, wtr, wti);
    dft_kernel<<<2048, 256, 0, stream>>>(x, Xp);
    mix_kernel<<<64, 256, 0, stream>>>(Xp, wtr, wti, yc);
    synth_kernel<<<4096, 256, 0, stream>>>(yc, out);
}